// Round 5
// baseline (660.768 us; speedup 1.0000x reference)
//
#include <hip/hip_runtime.h>

#define NTB 25

typedef float f32x4 __attribute__((ext_vector_type(4)));
typedef short bf16x8 __attribute__((ext_vector_type(8)));

__device__ __forceinline__ ushort f2bf(float f) {
    union { float f; uint u; } v; v.f = f;
    uint u = v.u;
    return (ushort)((u + 0x7fffu + ((u >> 16) & 1u)) >> 16);
}
__device__ __forceinline__ float bf2f(ushort h) {
    union { uint u; float f; } v; v.u = ((uint)h) << 16;
    return v.f;
}

// ---------------- K0: all weights f32 -> bf16 once ----------------
// gwb[128][256], twb[128][256], Wbf[256][128]
__global__ __launch_bounds__(256) void k0_wconv(
    const float* __restrict__ gw, const float* __restrict__ tw,
    const float* __restrict__ Ww,
    ushort* __restrict__ gwb, ushort* __restrict__ twb, ushort* __restrict__ Wbf)
{
    int idx = blockIdx.x * 256 + threadIdx.x;
    if (idx < 32768) gwb[idx] = f2bf(gw[idx]);
    else if (idx < 65536) twb[idx - 32768] = f2bf(tw[idx - 32768]);
    else if (idx < 98304) Wbf[idx - 65536] = f2bf(Ww[idx - 65536]);
}

// ---------------- K1a: transpose/convert x f32[b][c][n] -> xT bf16[b][n][c] ----------------
__global__ __launch_bounds__(256) void k1a_xpose(const float* __restrict__ x,
                                                 ushort* __restrict__ xT)
{
    int blk = blockIdx.x;
    int nt = blk % NTB; blk /= NTB;
    int cb = blk & 3; int b = blk >> 2;
    int n0 = nt * 64, c0 = cb * 64;
    __shared__ ushort lds[64 * 70];   // [c][n], pitch 70 u16
    int tid = threadIdx.x;

    const float* xb = x + ((size_t)b * 256 + c0) * 1600 + n0;
    #pragma unroll
    for (int p = 0; p < 4; ++p) {
        int idx = tid + p * 256;          // 0..1023
        int c = idx >> 4, n4 = idx & 15;
        float4 v = *reinterpret_cast<const float4*>(&xb[(size_t)c * 1600 + n4 * 4]);
        ushort4 pk;
        pk.x = f2bf(v.x); pk.y = f2bf(v.y); pk.z = f2bf(v.z); pk.w = f2bf(v.w);
        *reinterpret_cast<ushort4*>(&lds[c * 70 + n4 * 4]) = pk;
    }
    __syncthreads();
    ushort* xo = xT + ((size_t)b * 1600 + n0) * 256 + c0;
    #pragma unroll
    for (int q = 0; q < 2; ++q) {
        int t2 = tid + q * 256;           // 0..511
        int n = t2 >> 3, c8 = t2 & 7;
        bf16x8 r;
        #pragma unroll
        for (int j = 0; j < 8; ++j)
            r[j] = (short)lds[(c8 * 8 + j) * 70 + n];
        *reinterpret_cast<bf16x8*>(&xo[(size_t)n * 256 + c8 * 8]) = r;
    }
}

// ---------------- K1b: barrier-free dual conv1x1 via MFMA ----------------
// waves 0,1: gout[b][o][n] = gw@x ; waves 2,3: thT[b][n][o] = tw@x
__global__ __launch_bounds__(256) void k1b_conv(
    const ushort* __restrict__ xT,
    const ushort* __restrict__ gwb, const float* __restrict__ gb,
    const ushort* __restrict__ twb, const float* __restrict__ tb,
    ushort* __restrict__ gout, ushort* __restrict__ thT)
{
    int nt = blockIdx.x % NTB, b = blockIdx.x / NTB;
    int n0 = nt * 64;
    int tid = threadIdx.x, lane = tid & 63, w = tid >> 6;
    int lr = lane & 15, lg = lane >> 4;
    const ushort* xb = xT + (size_t)b * 1600 * 256;

    if (w < 2) {
        // A = xT (rows n), B = gwb (cols o). D: row=n, col=o.
        int o0 = w * 64;
        f32x4 acc[4][4] = {};   // [mi: n][ni: o]
        #pragma unroll
        for (int kc = 0; kc < 8; ++kc) {
            bf16x8 a[4], bf[4];
            #pragma unroll
            for (int mi = 0; mi < 4; ++mi)
                a[mi] = *reinterpret_cast<const bf16x8*>(
                    &xb[(size_t)(n0 + mi * 16 + lr) * 256 + kc * 32 + lg * 8]);
            #pragma unroll
            for (int ni = 0; ni < 4; ++ni)
                bf[ni] = *reinterpret_cast<const bf16x8*>(
                    &gwb[(size_t)(o0 + ni * 16 + lr) * 256 + kc * 32 + lg * 8]);
            #pragma unroll
            for (int mi = 0; mi < 4; ++mi)
                #pragma unroll
                for (int ni = 0; ni < 4; ++ni)
                    acc[mi][ni] = __builtin_amdgcn_mfma_f32_16x16x32_bf16(
                        a[mi], bf[ni], acc[mi][ni], 0, 0, 0);
        }
        #pragma unroll
        for (int ni = 0; ni < 4; ++ni) {
            int o = o0 + ni * 16 + lr;
            float bs = gb[o];
            ushort* gp = &gout[((size_t)b * 128 + o) * 1600 + n0];
            #pragma unroll
            for (int mi = 0; mi < 4; ++mi) {
                ushort4 pk;
                pk.x = f2bf(acc[mi][ni][0] + bs);
                pk.y = f2bf(acc[mi][ni][1] + bs);
                pk.z = f2bf(acc[mi][ni][2] + bs);
                pk.w = f2bf(acc[mi][ni][3] + bs);
                *reinterpret_cast<ushort4*>(&gp[mi * 16 + lg * 4]) = pk;
            }
        }
    } else {
        // A = twb (rows o), B = xT (cols n). D: row=o, col=n.
        int o0 = (w - 2) * 64;
        f32x4 acc[4][4] = {};   // [mi: o][ni: n]
        #pragma unroll
        for (int kc = 0; kc < 8; ++kc) {
            bf16x8 a[4], bf[4];
            #pragma unroll
            for (int mi = 0; mi < 4; ++mi)
                a[mi] = *reinterpret_cast<const bf16x8*>(
                    &twb[(size_t)(o0 + mi * 16 + lr) * 256 + kc * 32 + lg * 8]);
            #pragma unroll
            for (int ni = 0; ni < 4; ++ni)
                bf[ni] = *reinterpret_cast<const bf16x8*>(
                    &xb[(size_t)(n0 + ni * 16 + lr) * 256 + kc * 32 + lg * 8]);
            #pragma unroll
            for (int mi = 0; mi < 4; ++mi)
                #pragma unroll
                for (int ni = 0; ni < 4; ++ni)
                    acc[mi][ni] = __builtin_amdgcn_mfma_f32_16x16x32_bf16(
                        a[mi], bf[ni], acc[mi][ni], 0, 0, 0);
        }
        #pragma unroll
        for (int mi = 0; mi < 4; ++mi) {
            float4 tbv = *reinterpret_cast<const float4*>(&tb[o0 + mi * 16 + lg * 4]);
            float tbb[4] = {tbv.x, tbv.y, tbv.z, tbv.w};
            #pragma unroll
            for (int ni = 0; ni < 4; ++ni) {
                int n = n0 + ni * 16 + lr;
                ushort4 pk;
                pk.x = f2bf(acc[mi][ni][0] + tbb[0]);
                pk.y = f2bf(acc[mi][ni][1] + tbb[1]);
                pk.z = f2bf(acc[mi][ni][2] + tbb[2]);
                pk.w = f2bf(acc[mi][ni][3] + tbb[3]);
                *reinterpret_cast<ushort4*>(
                    &thT[((size_t)b * 1600 + n) * 128 + o0 + mi * 16 + lg * 4]) = pk;
            }
        }
    }
}

// ---------------- K2: PSP pooling (faithful raw reshape), both phi layouts ----------------
__global__ __launch_bounds__(256) void k2a_psp(const ushort* __restrict__ g,
                                               ushort* __restrict__ phiC,
                                               ushort* __restrict__ phiT)
{
    int idx = blockIdx.x * 256 + threadIdx.x;
    if (idx >= 64 * 128 * 768) return;
    int j = idx % 768;
    int bc = idx / 768;
    float outv = 0.f;
    if (j < 725) {
        int ls, off;
        if (j < 25)       { ls = 0; off = 0; }
        else if (j < 125) { ls = 2; off = 25; }
        else if (j < 325) { ls = 3; off = 125; }
        else              { ls = 4; off = 325; }
        int m = j - off;
        int flat = (bc << ls) * 25 + m;
        int a   = flat >> (7 + ls);
        int rem = flat & ((128 << ls) - 1);
        int c2  = rem >> ls;
        int k   = rem & ((1 << ls) - 1);
        int L   = 64 >> ls;
        const ushort* p = g + ((size_t)a << 13) + (c2 << 6) + k * L;
        float sum = 0.f;
        for (int q = 0; q < L; ++q) sum += bf2f(p[q]);
        outv = sum * (1.f / L);
    }
    ushort hv = f2bf(outv);
    phiC[idx] = hv;
    int b = bc >> 7, c = bc & 127;
    phiT[((size_t)b * 768 + j) * 128 + c] = hv;
}

// ---------------- K3: E = exp(theta^T phi) (bf16) + column-sum partials ----------------
__global__ __launch_bounds__(256) void k3_expf(
    const ushort* __restrict__ thT, const ushort* __restrict__ phiT,
    ushort* __restrict__ E, float* __restrict__ psum, int b0)
{
    int blk = blockIdx.x;
    int st = blk % 12; blk /= 12;
    int nt = blk % 25; int bl = blk / 25;
    int b = b0 + bl;
    int n0 = nt * 64, s0 = st * 64;
    int tid = threadIdx.x, lane = tid & 63, w = tid >> 6;
    int lr = lane & 15, lg = lane >> 4;
    int nrow = n0 + w * 16;

    __shared__ float red[64][4];

    f32x4 acc[4] = {};
    #pragma unroll
    for (int kc = 0; kc < 4; ++kc) {
        bf16x8 a = *reinterpret_cast<const bf16x8*>(
            &thT[((size_t)b * 1600 + nrow + lr) * 128 + kc * 32 + lg * 8]);
        #pragma unroll
        for (int ni = 0; ni < 4; ++ni) {
            bf16x8 bb = *reinterpret_cast<const bf16x8*>(
                &phiT[((size_t)b * 768 + s0 + ni * 16 + lr) * 128 + kc * 32 + lg * 8]);
            acc[ni] = __builtin_amdgcn_mfma_f32_16x16x32_bf16(a, bb, acc[ni], 0, 0, 0);
        }
    }

    #pragma unroll
    for (int ni = 0; ni < 4; ++ni) {
        float se = 0.f;
        float ex[4];
        #pragma unroll
        for (int r = 0; r < 4; ++r) { ex[r] = __expf(acc[ni][r]); se += ex[r]; }
        #pragma unroll
        for (int r = 0; r < 4; ++r)
            E[((size_t)bl * 1600 + nrow + lg * 4 + r) * 768 + s0 + ni * 16 + lr] = f2bf(ex[r]);
        se += __shfl_xor(se, 16);
        se += __shfl_xor(se, 32);
        if (lg == 0) red[ni * 16 + lr][w] = se;
    }
    __syncthreads();
    if (tid < 64) {
        float z = red[tid][0] + red[tid][1] + red[tid][2] + red[tid][3];
        psum[((size_t)b * 768 + s0 + tid) * 25 + nt] = z;
    }
}

// ---------------- K4: Z combine + phiZ[c][s] = phi[c][s]/Z[s] ----------------
__global__ __launch_bounds__(256) void k4_phiz(const float* __restrict__ psum,
                                               const ushort* __restrict__ phiC,
                                               ushort* __restrict__ phiZ)
{
    int idx = blockIdx.x * 256 + threadIdx.x;
    if (idx >= 64 * 768) return;
    int s = idx % 768, b = idx / 768;
    const float* p = psum + (size_t)idx * 25;
    float z = 0.f;
    #pragma unroll
    for (int i = 0; i < 25; ++i) z += p[i];
    float zi = (s < 725) ? 1.f / z : 0.f;
    for (int c = 0; c < 128; ++c) {
        size_t off = ((size_t)b * 128 + c) * 768 + s;
        phiZ[off] = f2bf(bf2f(phiC[off]) * zi);
    }
}

// ---------------- K5: y = E @ phiZ^T (barrier-free GEMM) + col-sum partials of exp(y) ----------------
__global__ __launch_bounds__(256) void k5_pv(
    const ushort* __restrict__ E, const ushort* __restrict__ phiZ,
    ushort* __restrict__ y, float* __restrict__ ypz, int b0)
{
    int nt = blockIdx.x % NTB, bl = blockIdx.x / NTB;
    int b = b0 + bl;
    int n0 = nt * 64;
    int tid = threadIdx.x, lane = tid & 63, w = tid >> 6;
    int lr = lane & 15, lg = lane >> 4;
    int nrow = n0 + w * 16;
    const ushort* Eb = E + (size_t)bl * 1600 * 768;
    const ushort* Pb = phiZ + (size_t)b * 128 * 768;

    __shared__ float yred[4][128];

    f32x4 acc[8] = {};
    #pragma unroll 4
    for (int kc = 0; kc < 24; ++kc) {
        bf16x8 a = *reinterpret_cast<const bf16x8*>(
            &Eb[(size_t)(nrow + lr) * 768 + kc * 32 + lg * 8]);
        #pragma unroll
        for (int cf = 0; cf < 8; ++cf) {
            bf16x8 bb = *reinterpret_cast<const bf16x8*>(
                &Pb[(size_t)(cf * 16 + lr) * 768 + kc * 32 + lg * 8]);
            acc[cf] = __builtin_amdgcn_mfma_f32_16x16x32_bf16(a, bb, acc[cf], 0, 0, 0);
        }
    }

    #pragma unroll
    for (int cf = 0; cf < 8; ++cf) {
        float se = 0.f;
        #pragma unroll
        for (int r = 0; r < 4; ++r) {
            ushort hv = f2bf(acc[cf][r]);
            y[((size_t)b * 1600 + nrow + lg * 4 + r) * 128 + cf * 16 + lr] = hv;
            se += __expf(bf2f(hv));
        }
        se += __shfl_xor(se, 16);
        se += __shfl_xor(se, 32);
        if (lane < 16) yred[w][cf * 16 + lane] = se;
    }
    __syncthreads();
    if (tid < 128) {
        float p = yred[0][tid] + yred[1][tid] + yred[2][tid] + yred[3][tid];
        ypz[((size_t)b * 128 + tid) * 25 + nt] = p;
    }
}

// ---------------- K6b: combine 25 partials -> 1/Z2 per (b,c) ----------------
__global__ void k6b_ycomb(const float* __restrict__ ypz, float* __restrict__ yzi)
{
    int idx = blockIdx.x * 256 + threadIdx.x;
    if (idx >= 64 * 128) return;
    const float* p = ypz + (size_t)idx * 25;
    float z = 0.f;
    #pragma unroll
    for (int i = 0; i < 25; ++i) z += p[i];
    yzi[idx] = 1.f / z;
}

// ---------------- K7: softmax(y) -> conv W (MFMA) + residual + BN + ReLU ----------------
__global__ __launch_bounds__(256) void k7_final(
    const ushort* __restrict__ y, const float* __restrict__ yzi,
    const ushort* __restrict__ Wbf, const float* __restrict__ Wb,
    const float* __restrict__ x,
    const float* __restrict__ gamma, const float* __restrict__ beta,
    const float* __restrict__ mean, const float* __restrict__ var,
    float* __restrict__ out)
{
    int nt = blockIdx.x % NTB, b = blockIdx.x / NTB;
    int n0 = nt * 64;
    __shared__ ushort yl[64][136];
    __shared__ float scl[256], shl[256], wbl[256], zl[128];
    int t = threadIdx.x, lane = t & 63, w = t >> 6;
    {
        float sc = gamma[t] * rsqrtf(var[t] + 1e-5f);
        scl[t] = sc;
        shl[t] = beta[t] - mean[t] * sc;
        wbl[t] = Wb[t];
        if (t < 128) zl[t] = yzi[(size_t)b * 128 + t];
    }
    __syncthreads();
    int c8 = (t & 15) * 8, rr = t >> 4;
    #pragma unroll
    for (int p = 0; p < 4; ++p) {
        int r = rr + 16 * p;
        bf16x8 v = *reinterpret_cast<const bf16x8*>(
            &y[((size_t)b * 1600 + n0 + r) * 128 + c8]);
        bf16x8 pk;
        #pragma unroll
        for (int j = 0; j < 8; ++j) {
            float f = bf2f((ushort)v[j]);
            pk[j] = (short)f2bf(__expf(f) * zl[c8 + j]);
        }
        *reinterpret_cast<bf16x8*>(&yl[r][c8]) = pk;
    }
    __syncthreads();
    int lr = lane & 15, lg = lane >> 4;
    int o0 = w * 64;
    f32x4 acc[4][4] = {};
    #pragma unroll
    for (int kc = 0; kc < 4; ++kc) {
        bf16x8 af[4];
        #pragma unroll
        for (int mi = 0; mi < 4; ++mi)
            af[mi] = *reinterpret_cast<const bf16x8*>(
                &Wbf[(size_t)(o0 + mi * 16 + lr) * 128 + kc * 32 + lg * 8]);
        #pragma unroll
        for (int ni = 0; ni < 4; ++ni) {
            bf16x8 bfrag = *reinterpret_cast<const bf16x8*>(&yl[ni * 16 + lr][kc * 32 + lg * 8]);
            #pragma unroll
            for (int mi = 0; mi < 4; ++mi)
                acc[mi][ni] = __builtin_amdgcn_mfma_f32_16x16x32_bf16(
                    af[mi], bfrag, acc[mi][ni], 0, 0, 0);
        }
    }
    #pragma unroll
    for (int mi = 0; mi < 4; ++mi)
        #pragma unroll
        for (int ni = 0; ni < 4; ++ni) {
            int n = n0 + ni * 16 + lr;
            #pragma unroll
            for (int r = 0; r < 4; ++r) {
                int o = o0 + mi * 16 + lg * 4 + r;
                size_t off = ((size_t)b * 256 + o) * 1600 + n;
                float v = (acc[mi][ni][r] + wbl[o] + x[off]) * scl[o] + shl[o];
                out[off] = fmaxf(v, 0.f);
            }
        }
}

extern "C" void kernel_launch(void* const* d_in, const int* in_sizes, int n_in,
                              void* d_out, int out_size, void* d_ws, size_t ws_size,
                              hipStream_t stream)
{
    const float* x   = (const float*)d_in[0];
    const float* gw  = (const float*)d_in[1];
    const float* gb  = (const float*)d_in[2];
    const float* tw  = (const float*)d_in[3];
    const float* tb  = (const float*)d_in[4];
    const float* Ww  = (const float*)d_in[5];
    const float* Wb  = (const float*)d_in[6];
    const float* bng = (const float*)d_in[7];
    const float* bnb = (const float*)d_in[8];
    const float* bnm = (const float*)d_in[9];
    const float* bnv = (const float*)d_in[10];
    float* out = (float*)d_out;

    char* base = (char*)d_ws;
    ushort* thT  = (ushort*)(base);               // 26,214,400 B
    ushort* gout = (ushort*)(base + 26214400);    // 26,214,400 B (reused as y)
    ushort* phiC = (ushort*)(base + 52428800);    // 12,582,912 B
    ushort* phiT = (ushort*)(base + 65011712);    // 12,582,912 B
    float* psum  = (float*)(base + 77594624);     //  4,915,200 B
    ushort* phiZ = (ushort*)(base + 82509824);    // 12,582,912 B
    float* ypz   = (float*)(base + 95092736);     //    819,200 B
    float* yzi   = (float*)(base + 95911936);     //     32,768 B
    ushort* Wbf  = (ushort*)(base + 95944704);    //     65,536 B
    ushort* gwb  = (ushort*)(base + 96010240);    //     65,536 B
    ushort* twb  = (ushort*)(base + 96075776);    //     65,536 B
    ushort* yv   = gout;                          // alias: gout dead after k2a
    // d_out region (104,857,600 B) is sequential scratch:
    //   xT (52,428,800 B, dead after k1b) then E (78,643,200 B/half, dead after k5).
    // k7 fully rewrites out last.
    ushort* xT   = (ushort*)d_out;
    ushort* E    = (ushort*)d_out;

    k0_wconv<<<384, 256, 0, stream>>>(gw, tw, Ww, gwb, twb, Wbf);
    k1a_xpose<<<64 * 4 * NTB, 256, 0, stream>>>(x, xT);
    k1b_conv<<<64 * NTB, 256, 0, stream>>>(xT, gwb, gb, twb, tb, gout, thT);
    k2a_psp<<<(64 * 128 * 768) / 256, 256, 0, stream>>>(gout, phiC, phiT);

    // half 0: batches 0..31
    k3_expf<<<32 * 25 * 12, 256, 0, stream>>>(thT, phiT, E, psum, 0);
    k4_phiz<<<(32 * 768) / 256, 256, 0, stream>>>(psum, phiC, phiZ);
    k5_pv<<<32 * NTB, 256, 0, stream>>>(E, phiZ, yv, ypz, 0);

    // half 1: batches 32..63
    k3_expf<<<32 * 25 * 12, 256, 0, stream>>>(thT, phiT, E, psum, 32);
    k4_phiz<<<(32 * 768) / 256, 256, 0, stream>>>(psum + (size_t)32 * 768 * 25,
                                                  phiC + (size_t)32 * 128 * 768,
                                                  phiZ + (size_t)32 * 128 * 768);
    k5_pv<<<32 * NTB, 256, 0, stream>>>(E, phiZ, yv, ypz, 32);

    k6b_ycomb<<<32, 256, 0, stream>>>(ypz, yzi);
    k7_final<<<64 * NTB, 256, 0, stream>>>(yv, yzi, Wbf, Wb, x, bng, bnb, bnm, bnv, out);
}

// Round 6
// 612.216 us; speedup vs baseline: 1.0793x; 1.0793x over previous
//
#include <hip/hip_runtime.h>

#define NTB 25

typedef float f32x4 __attribute__((ext_vector_type(4)));
typedef short bf16x8 __attribute__((ext_vector_type(8)));

__device__ __forceinline__ ushort f2bf(float f) {
    union { float f; uint u; } v; v.f = f;
    uint u = v.u;
    return (ushort)((u + 0x7fffu + ((u >> 16) & 1u)) >> 16);
}
__device__ __forceinline__ float bf2f(ushort h) {
    union { uint u; float f; } v; v.u = ((uint)h) << 16;
    return v.f;
}

// ---------------- K0: all weights f32 -> bf16 once ----------------
__global__ __launch_bounds__(256) void k0_wconv(
    const float* __restrict__ gw, const float* __restrict__ tw,
    const float* __restrict__ Ww,
    ushort* __restrict__ gwb, ushort* __restrict__ twb, ushort* __restrict__ Wbf)
{
    int idx = blockIdx.x * 256 + threadIdx.x;
    if (idx < 32768) gwb[idx] = f2bf(gw[idx]);
    else if (idx < 65536) twb[idx - 32768] = f2bf(tw[idx - 32768]);
    else if (idx < 98304) Wbf[idx - 65536] = f2bf(Ww[idx - 65536]);
}

// ---------------- K1a: transpose/convert x f32[b][c][n] -> xT bf16[b][n][c] ----------------
__global__ __launch_bounds__(256) void k1a_xpose(const float* __restrict__ x,
                                                 ushort* __restrict__ xT)
{
    int blk = blockIdx.x;
    int nt = blk % NTB; blk /= NTB;
    int cb = blk & 3; int b = blk >> 2;
    int n0 = nt * 64, c0 = cb * 64;
    __shared__ ushort lds[64 * 70];
    int tid = threadIdx.x;

    const float* xb = x + ((size_t)b * 256 + c0) * 1600 + n0;
    #pragma unroll
    for (int p = 0; p < 4; ++p) {
        int idx = tid + p * 256;
        int c = idx >> 4, n4 = idx & 15;
        float4 v = *reinterpret_cast<const float4*>(&xb[(size_t)c * 1600 + n4 * 4]);
        ushort4 pk;
        pk.x = f2bf(v.x); pk.y = f2bf(v.y); pk.z = f2bf(v.z); pk.w = f2bf(v.w);
        *reinterpret_cast<ushort4*>(&lds[c * 70 + n4 * 4]) = pk;
    }
    __syncthreads();
    ushort* xo = xT + ((size_t)b * 1600 + n0) * 256 + c0;
    #pragma unroll
    for (int q = 0; q < 2; ++q) {
        int t2 = tid + q * 256;
        int n = t2 >> 3, c8 = t2 & 7;
        bf16x8 r;
        #pragma unroll
        for (int j = 0; j < 8; ++j)
            r[j] = (short)lds[(c8 * 8 + j) * 70 + n];
        *reinterpret_cast<bf16x8*>(&xo[(size_t)n * 256 + c8 * 8]) = r;
    }
}

// ---------------- K1b: barrier-free dual conv1x1 via MFMA ----------------
__global__ __launch_bounds__(256) void k1b_conv(
    const ushort* __restrict__ xT,
    const ushort* __restrict__ gwb, const float* __restrict__ gb,
    const ushort* __restrict__ twb, const float* __restrict__ tb,
    ushort* __restrict__ gout, ushort* __restrict__ thT)
{
    int nt = blockIdx.x % NTB, b = blockIdx.x / NTB;
    int n0 = nt * 64;
    int tid = threadIdx.x, lane = tid & 63, w = tid >> 6;
    int lr = lane & 15, lg = lane >> 4;
    const ushort* xb = xT + (size_t)b * 1600 * 256;

    if (w < 2) {
        int o0 = w * 64;
        f32x4 acc[4][4] = {};
        #pragma unroll
        for (int kc = 0; kc < 8; ++kc) {
            bf16x8 a[4], bf[4];
            #pragma unroll
            for (int mi = 0; mi < 4; ++mi)
                a[mi] = *reinterpret_cast<const bf16x8*>(
                    &xb[(size_t)(n0 + mi * 16 + lr) * 256 + kc * 32 + lg * 8]);
            #pragma unroll
            for (int ni = 0; ni < 4; ++ni)
                bf[ni] = *reinterpret_cast<const bf16x8*>(
                    &gwb[(size_t)(o0 + ni * 16 + lr) * 256 + kc * 32 + lg * 8]);
            #pragma unroll
            for (int mi = 0; mi < 4; ++mi)
                #pragma unroll
                for (int ni = 0; ni < 4; ++ni)
                    acc[mi][ni] = __builtin_amdgcn_mfma_f32_16x16x32_bf16(
                        a[mi], bf[ni], acc[mi][ni], 0, 0, 0);
        }
        #pragma unroll
        for (int ni = 0; ni < 4; ++ni) {
            int o = o0 + ni * 16 + lr;
            float bs = gb[o];
            ushort* gp = &gout[((size_t)b * 128 + o) * 1600 + n0];
            #pragma unroll
            for (int mi = 0; mi < 4; ++mi) {
                ushort4 pk;
                pk.x = f2bf(acc[mi][ni][0] + bs);
                pk.y = f2bf(acc[mi][ni][1] + bs);
                pk.z = f2bf(acc[mi][ni][2] + bs);
                pk.w = f2bf(acc[mi][ni][3] + bs);
                *reinterpret_cast<ushort4*>(&gp[mi * 16 + lg * 4]) = pk;
            }
        }
    } else {
        int o0 = (w - 2) * 64;
        f32x4 acc[4][4] = {};
        #pragma unroll
        for (int kc = 0; kc < 8; ++kc) {
            bf16x8 a[4], bf[4];
            #pragma unroll
            for (int mi = 0; mi < 4; ++mi)
                a[mi] = *reinterpret_cast<const bf16x8*>(
                    &twb[(size_t)(o0 + mi * 16 + lr) * 256 + kc * 32 + lg * 8]);
            #pragma unroll
            for (int ni = 0; ni < 4; ++ni)
                bf[ni] = *reinterpret_cast<const bf16x8*>(
                    &xb[(size_t)(n0 + ni * 16 + lr) * 256 + kc * 32 + lg * 8]);
            #pragma unroll
            for (int mi = 0; mi < 4; ++mi)
                #pragma unroll
                for (int ni = 0; ni < 4; ++ni)
                    acc[mi][ni] = __builtin_amdgcn_mfma_f32_16x16x32_bf16(
                        a[mi], bf[ni], acc[mi][ni], 0, 0, 0);
        }
        #pragma unroll
        for (int mi = 0; mi < 4; ++mi) {
            float4 tbv = *reinterpret_cast<const float4*>(&tb[o0 + mi * 16 + lg * 4]);
            float tbb[4] = {tbv.x, tbv.y, tbv.z, tbv.w};
            #pragma unroll
            for (int ni = 0; ni < 4; ++ni) {
                int n = n0 + ni * 16 + lr;
                ushort4 pk;
                pk.x = f2bf(acc[mi][ni][0] + tbb[0]);
                pk.y = f2bf(acc[mi][ni][1] + tbb[1]);
                pk.z = f2bf(acc[mi][ni][2] + tbb[2]);
                pk.w = f2bf(acc[mi][ni][3] + tbb[3]);
                *reinterpret_cast<ushort4*>(
                    &thT[((size_t)b * 1600 + n) * 128 + o0 + mi * 16 + lg * 4]) = pk;
            }
        }
    }
}

// ---------------- K2: PSP pooling (faithful raw reshape), both phi layouts ----------------
__global__ __launch_bounds__(256) void k2a_psp(const ushort* __restrict__ g,
                                               ushort* __restrict__ phiC,
                                               ushort* __restrict__ phiT)
{
    int idx = blockIdx.x * 256 + threadIdx.x;
    if (idx >= 64 * 128 * 768) return;
    int j = idx % 768;
    int bc = idx / 768;
    float outv = 0.f;
    if (j < 725) {
        int ls, off;
        if (j < 25)       { ls = 0; off = 0; }
        else if (j < 125) { ls = 2; off = 25; }
        else if (j < 325) { ls = 3; off = 125; }
        else              { ls = 4; off = 325; }
        int m = j - off;
        int flat = (bc << ls) * 25 + m;
        int a   = flat >> (7 + ls);
        int rem = flat & ((128 << ls) - 1);
        int c2  = rem >> ls;
        int k   = rem & ((1 << ls) - 1);
        int L   = 64 >> ls;
        const ushort* p = g + ((size_t)a << 13) + (c2 << 6) + k * L;
        float sum = 0.f;
        for (int q = 0; q < L; ++q) sum += bf2f(p[q]);
        outv = sum * (1.f / L);
    }
    ushort hv = f2bf(outv);
    phiC[idx] = hv;
    int b = bc >> 7, c = bc & 127;
    phiT[((size_t)b * 768 + j) * 128 + c] = hv;
}

// ---------------- K3: E = exp(theta^T phi) (bf16) + column-sum partials ----------------
__global__ __launch_bounds__(256, 2) void k3_expf(
    const ushort* __restrict__ thT, const ushort* __restrict__ phiT,
    ushort* __restrict__ E, float* __restrict__ psum, int b0)
{
    int blk = blockIdx.x;
    int st = blk % 12; blk /= 12;
    int nt = blk % 25; int bl = blk / 25;
    int b = b0 + bl;
    int n0 = nt * 64, s0 = st * 64;
    int tid = threadIdx.x, lane = tid & 63, w = tid >> 6;
    int lr = lane & 15, lg = lane >> 4;
    int nrow = n0 + w * 16;

    __shared__ float red[64][4];

    // hoist all 20 fragment loads (full MLP), then MFMA
    bf16x8 A[4], B[4][4];
    #pragma unroll
    for (int kc = 0; kc < 4; ++kc) {
        A[kc] = *reinterpret_cast<const bf16x8*>(
            &thT[((size_t)b * 1600 + nrow + lr) * 128 + kc * 32 + lg * 8]);
        #pragma unroll
        for (int ni = 0; ni < 4; ++ni)
            B[kc][ni] = *reinterpret_cast<const bf16x8*>(
                &phiT[((size_t)b * 768 + s0 + ni * 16 + lr) * 128 + kc * 32 + lg * 8]);
    }
    f32x4 acc[4] = {};
    #pragma unroll
    for (int kc = 0; kc < 4; ++kc)
        #pragma unroll
        for (int ni = 0; ni < 4; ++ni)
            acc[ni] = __builtin_amdgcn_mfma_f32_16x16x32_bf16(A[kc], B[kc][ni], acc[ni], 0, 0, 0);

    #pragma unroll
    for (int ni = 0; ni < 4; ++ni) {
        float se = 0.f;
        float ex[4];
        #pragma unroll
        for (int r = 0; r < 4; ++r) { ex[r] = __expf(acc[ni][r]); se += ex[r]; }
        #pragma unroll
        for (int r = 0; r < 4; ++r)
            E[((size_t)bl * 1600 + nrow + lg * 4 + r) * 768 + s0 + ni * 16 + lr] = f2bf(ex[r]);
        se += __shfl_xor(se, 16);
        se += __shfl_xor(se, 32);
        if (lg == 0) red[ni * 16 + lr][w] = se;
    }
    __syncthreads();
    if (tid < 64) {
        float z = red[tid][0] + red[tid][1] + red[tid][2] + red[tid][3];
        psum[((size_t)b * 768 + s0 + tid) * 25 + nt] = z;
    }
}

// ---------------- K4a: zinv[b][s] = 1/sum(psum partials) ----------------
__global__ __launch_bounds__(256) void k4a_zinv(const float* __restrict__ psum,
                                                float* __restrict__ zinv)
{
    int idx = blockIdx.x * 256 + threadIdx.x;
    if (idx >= 32 * 768) return;
    int s = idx % 768;
    const float* p = psum + (size_t)idx * 25;
    float z = 0.f;
    #pragma unroll
    for (int i = 0; i < 25; ++i) z += p[i];
    zinv[idx] = (s < 725) ? 1.f / z : 0.f;
}

// ---------------- K4b: phiZ = phiC * zinv[s], coalesced bf16x8 ----------------
__global__ __launch_bounds__(256) void k4b_scale(const ushort* __restrict__ phiC,
                                                 const float* __restrict__ zinv,
                                                 ushort* __restrict__ phiZ)
{
    int idx = blockIdx.x * 256 + threadIdx.x;   // 32*128*96
    int s8 = idx % 96, bc = idx / 96;
    int b = bc >> 7;
    size_t off = (size_t)bc * 768 + s8 * 8;
    bf16x8 v = *reinterpret_cast<const bf16x8*>(&phiC[off]);
    const float* zp = &zinv[b * 768 + s8 * 8];
    bf16x8 r;
    #pragma unroll
    for (int j = 0; j < 8; ++j) r[j] = (short)f2bf(bf2f((ushort)v[j]) * zp[j]);
    *reinterpret_cast<bf16x8*>(&phiZ[off]) = r;
}

// ---------------- K5: y = E @ phiZ^T, single-wave blocks, depth-3 reg prefetch ----------------
__global__ __launch_bounds__(64, 2) void k5_pv(
    const ushort* __restrict__ E, const ushort* __restrict__ phiZ,
    ushort* __restrict__ y, float* __restrict__ ypz, int b0)
{
    int ng = blockIdx.x % 100, bl = blockIdx.x / 100;
    int b = b0 + bl;
    int nrow = ng * 16;
    int lane = threadIdx.x;
    int lr = lane & 15, lg = lane >> 4;
    const ushort* Eb = E + (size_t)bl * 1600 * 768;
    const ushort* Pb = phiZ + (size_t)b * 128 * 768;

    f32x4 acc[8] = {};
    bf16x8 Ab[3], Bb[3][8];
    #pragma unroll
    for (int p = 0; p < 3; ++p) {
        Ab[p] = *reinterpret_cast<const bf16x8*>(
            &Eb[(size_t)(nrow + lr) * 768 + p * 32 + lg * 8]);
        #pragma unroll
        for (int cf = 0; cf < 8; ++cf)
            Bb[p][cf] = *reinterpret_cast<const bf16x8*>(
                &Pb[(size_t)(cf * 16 + lr) * 768 + p * 32 + lg * 8]);
    }
    #pragma unroll
    for (int kc = 0; kc < 24; ++kc) {
        int cur = kc % 3;
        bf16x8 a = Ab[cur];
        #pragma unroll
        for (int cf = 0; cf < 8; ++cf)
            acc[cf] = __builtin_amdgcn_mfma_f32_16x16x32_bf16(a, Bb[cur][cf], acc[cf], 0, 0, 0);
        if (kc + 3 < 24) {
            Ab[cur] = *reinterpret_cast<const bf16x8*>(
                &Eb[(size_t)(nrow + lr) * 768 + (kc + 3) * 32 + lg * 8]);
            #pragma unroll
            for (int cf = 0; cf < 8; ++cf)
                Bb[cur][cf] = *reinterpret_cast<const bf16x8*>(
                    &Pb[(size_t)(cf * 16 + lr) * 768 + (kc + 3) * 32 + lg * 8]);
        }
    }

    #pragma unroll
    for (int cf = 0; cf < 8; ++cf) {
        float se = 0.f;
        #pragma unroll
        for (int r = 0; r < 4; ++r) {
            ushort hv = f2bf(acc[cf][r]);
            y[((size_t)b * 1600 + nrow + lg * 4 + r) * 128 + cf * 16 + lr] = hv;
            se += __expf(bf2f(hv));
        }
        se += __shfl_xor(se, 16);
        se += __shfl_xor(se, 32);
        if (lane < 16)
            ypz[((size_t)b * 128 + cf * 16 + lane) * 100 + ng] = se;
    }
}

// ---------------- K6b: combine 100 partials -> 1/Z2 per (b,c) ----------------
__global__ void k6b_ycomb(const float* __restrict__ ypz, float* __restrict__ yzi)
{
    int idx = blockIdx.x * 256 + threadIdx.x;
    if (idx >= 64 * 128) return;
    const float* p = ypz + (size_t)idx * 100;
    float z = 0.f;
    for (int i = 0; i < 100; ++i) z += p[i];
    yzi[idx] = 1.f / z;
}

// ---------------- K7: softmax(y) -> conv W (MFMA) + residual + BN + ReLU ----------------
__global__ __launch_bounds__(256) void k7_final(
    const ushort* __restrict__ y, const float* __restrict__ yzi,
    const ushort* __restrict__ Wbf, const float* __restrict__ Wb,
    const float* __restrict__ x,
    const float* __restrict__ gamma, const float* __restrict__ beta,
    const float* __restrict__ mean, const float* __restrict__ var,
    float* __restrict__ out)
{
    int nt = blockIdx.x % NTB, b = blockIdx.x / NTB;
    int n0 = nt * 64;
    __shared__ ushort yl[64][136];
    __shared__ float scl[256], shl[256], wbl[256], zl[128];
    int t = threadIdx.x, lane = t & 63, w = t >> 6;
    {
        float sc = gamma[t] * rsqrtf(var[t] + 1e-5f);
        scl[t] = sc;
        shl[t] = beta[t] - mean[t] * sc;
        wbl[t] = Wb[t];
        if (t < 128) zl[t] = yzi[(size_t)b * 128 + t];
    }
    __syncthreads();
    int c8 = (t & 15) * 8, rr = t >> 4;
    #pragma unroll
    for (int p = 0; p < 4; ++p) {
        int r = rr + 16 * p;
        bf16x8 v = *reinterpret_cast<const bf16x8*>(
            &y[((size_t)b * 1600 + n0 + r) * 128 + c8]);
        bf16x8 pk;
        #pragma unroll
        for (int j = 0; j < 8; ++j) {
            float f = bf2f((ushort)v[j]);
            pk[j] = (short)f2bf(__expf(f) * zl[c8 + j]);
        }
        *reinterpret_cast<bf16x8*>(&yl[r][c8]) = pk;
    }
    __syncthreads();
    int lr = lane & 15, lg = lane >> 4;
    int o0 = w * 64;
    f32x4 acc[4][4] = {};
    #pragma unroll
    for (int kc = 0; kc < 4; ++kc) {
        bf16x8 af[4];
        #pragma unroll
        for (int mi = 0; mi < 4; ++mi)
            af[mi] = *reinterpret_cast<const bf16x8*>(
                &Wbf[(size_t)(o0 + mi * 16 + lr) * 128 + kc * 32 + lg * 8]);
        #pragma unroll
        for (int ni = 0; ni < 4; ++ni) {
            bf16x8 bfrag = *reinterpret_cast<const bf16x8*>(&yl[ni * 16 + lr][kc * 32 + lg * 8]);
            #pragma unroll
            for (int mi = 0; mi < 4; ++mi)
                acc[mi][ni] = __builtin_amdgcn_mfma_f32_16x16x32_bf16(
                    af[mi], bfrag, acc[mi][ni], 0, 0, 0);
        }
    }
    #pragma unroll
    for (int mi = 0; mi < 4; ++mi)
        #pragma unroll
        for (int ni = 0; ni < 4; ++ni) {
            int n = n0 + ni * 16 + lr;
            #pragma unroll
            for (int r = 0; r < 4; ++r) {
                int o = o0 + mi * 16 + lg * 4 + r;
                size_t off = ((size_t)b * 256 + o) * 1600 + n;
                float v = (acc[mi][ni][r] + wbl[o] + x[off]) * scl[o] + shl[o];
                out[off] = fmaxf(v, 0.f);
            }
        }
}

extern "C" void kernel_launch(void* const* d_in, const int* in_sizes, int n_in,
                              void* d_out, int out_size, void* d_ws, size_t ws_size,
                              hipStream_t stream)
{
    const float* x   = (const float*)d_in[0];
    const float* gw  = (const float*)d_in[1];
    const float* gb  = (const float*)d_in[2];
    const float* tw  = (const float*)d_in[3];
    const float* tb  = (const float*)d_in[4];
    const float* Ww  = (const float*)d_in[5];
    const float* Wb  = (const float*)d_in[6];
    const float* bng = (const float*)d_in[7];
    const float* bnb = (const float*)d_in[8];
    const float* bnm = (const float*)d_in[9];
    const float* bnv = (const float*)d_in[10];
    float* out = (float*)d_out;

    char* base = (char*)d_ws;
    ushort* thT  = (ushort*)(base);               // 26,214,400 B
    ushort* gout = (ushort*)(base + 26214400);    // 26,214,400 B (reused as y)
    ushort* phiC = (ushort*)(base + 52428800);    // 12,582,912 B
    ushort* phiT = (ushort*)(base + 65011712);    // 12,582,912 B
    float* psum  = (float*)(base + 77594624);     //  4,915,200 B
    ushort* phiZ = (ushort*)(base + 82509824);    // 12,582,912 B
    float* zinv  = (float*)(base + 95092736);     //    196,608 B (per half: 32*768)
    float* ypz   = (float*)(base + 95289344);     //  3,276,800 B (64*128*100)
    float* yzi   = (float*)(base + 98566144);     //     32,768 B
    ushort* Wbf  = (ushort*)(base + 98598912);    //     65,536 B
    ushort* gwb  = (ushort*)(base + 98664448);    //     65,536 B
    ushort* twb  = (ushort*)(base + 98729984);    //     65,536 B
    ushort* yv   = gout;                          // alias: gout dead after k2a
    // d_out region (104,857,600 B) as scratch: xT (52.4 MB, dead after k1b),
    // then E per half (78.6 MB, dead after k5). k7 fully rewrites out last.
    ushort* xT   = (ushort*)d_out;
    ushort* E    = (ushort*)d_out;

    k0_wconv<<<384, 256, 0, stream>>>(gw, tw, Ww, gwb, twb, Wbf);
    k1a_xpose<<<64 * 4 * NTB, 256, 0, stream>>>(x, xT);
    k1b_conv<<<64 * NTB, 256, 0, stream>>>(xT, gwb, gb, twb, tb, gout, thT);
    k2a_psp<<<(64 * 128 * 768) / 256, 256, 0, stream>>>(gout, phiC, phiT);

    // half 0: batches 0..31
    k3_expf<<<32 * 25 * 12, 256, 0, stream>>>(thT, phiT, E, psum, 0);
    k4a_zinv<<<96, 256, 0, stream>>>(psum, zinv);
    k4b_scale<<<1536, 256, 0, stream>>>(phiC, zinv, phiZ);
    k5_pv<<<32 * 100, 64, 0, stream>>>(E, phiZ, yv, ypz, 0);

    // half 1: batches 32..63
    k3_expf<<<32 * 25 * 12, 256, 0, stream>>>(thT, phiT, E, psum, 32);
    k4a_zinv<<<96, 256, 0, stream>>>(psum + (size_t)32 * 768 * 25, zinv);
    k4b_scale<<<1536, 256, 0, stream>>>(phiC + (size_t)32 * 128 * 768, zinv,
                                        phiZ + (size_t)32 * 128 * 768);
    k5_pv<<<32 * 100, 64, 0, stream>>>(E, phiZ, yv, ypz, 32);

    k6b_ycomb<<<32, 256, 0, stream>>>(ypz, yzi);
    k7_final<<<64 * NTB, 256, 0, stream>>>(yv, yzi, Wbf, Wb, x, bng, bnb, bnm, bnv, out);
}

// Round 7
// 376.848 us; speedup vs baseline: 1.7534x; 1.6246x over previous
//
#include <hip/hip_runtime.h>

#define NTB 25

typedef float f32x4 __attribute__((ext_vector_type(4)));
typedef short bf16x8 __attribute__((ext_vector_type(8)));

__device__ __forceinline__ ushort f2bf(float f) {
    union { float f; uint u; } v; v.f = f;
    uint u = v.u;
    return (ushort)((u + 0x7fffu + ((u >> 16) & 1u)) >> 16);
}
__device__ __forceinline__ float bf2f(ushort h) {
    union { uint u; float f; } v; v.u = ((uint)h) << 16;
    return v.f;
}
// fragment-block element offset: element (p, k32) of a 16x32 tile stored
// so that lane l owns u16 slots l*8..l*8+7 = (p=l&15, k=(l>>4)*8+j).
__device__ __forceinline__ int foff(int p, int k32) {
    return (((p & 15) | (((k32 >> 3) & 3) << 4)) << 3) + (k32 & 7);
}

// ---------------- K0: weights f32 -> frag-swizzled bf16 ----------------
// gwb/twb: rows o(128) x k c(256): blocks (o>>4)*8 + (c>>5).
// Wbf: rows o(256) x k c(128): blocks (o>>4)*4 + (c>>5).
__global__ __launch_bounds__(256) void k0_wconv(
    const float* __restrict__ gw, const float* __restrict__ tw,
    const float* __restrict__ Ww,
    ushort* __restrict__ gwb, ushort* __restrict__ twb, ushort* __restrict__ Wbf)
{
    int idx = blockIdx.x * 256 + threadIdx.x;
    if (idx < 8192) {
        const float* src = (idx < 4096) ? gw : tw;
        ushort* dst = (idx < 4096) ? gwb : twb;
        int u = idx & 4095;
        int o = u >> 5, c0 = (u & 31) << 3;
        ushort* d = dst + ((o >> 4) * 8 + (c0 >> 5)) * 512 + foff(o, c0 & 31);
        #pragma unroll
        for (int j = 0; j < 8; ++j) d[j] = f2bf(src[o * 256 + c0 + j]);
    } else if (idx < 12288) {
        int u = idx - 8192;
        int o = u >> 4, c0 = (u & 15) << 3;
        ushort* d = Wbf + ((o >> 4) * 4 + (c0 >> 5)) * 512 + foff(o, c0 & 31);
        #pragma unroll
        for (int j = 0; j < 8; ++j) d[j] = f2bf(Ww[o * 128 + c0 + j]);
    }
}

// ---------------- K1a: x f32[b][c][n] -> xT frag-swizzled bf16 (rows n, k c) ----------------
// xT blocks per b: (n>>4)*8 + (c>>5), 100*8 blocks, b stride 409600 u16.
__global__ __launch_bounds__(256) void k1a_xpose(const float* __restrict__ x,
                                                 ushort* __restrict__ xT)
{
    int blk = blockIdx.x;
    int nt = blk % NTB; blk /= NTB;
    int cb = blk & 3; int b = blk >> 2;
    int n0 = nt * 64, c0 = cb * 64;
    __shared__ ushort lds[64 * 70];
    int tid = threadIdx.x;

    const float* xb = x + ((size_t)b * 256 + c0) * 1600 + n0;
    #pragma unroll
    for (int p = 0; p < 4; ++p) {
        int idx = tid + p * 256;
        int c = idx >> 4, n4 = idx & 15;
        float4 v = *reinterpret_cast<const float4*>(&xb[(size_t)c * 1600 + n4 * 4]);
        ushort4 pk;
        pk.x = f2bf(v.x); pk.y = f2bf(v.y); pk.z = f2bf(v.z); pk.w = f2bf(v.w);
        *reinterpret_cast<ushort4*>(&lds[c * 70 + n4 * 4]) = pk;
    }
    __syncthreads();
    #pragma unroll
    for (int q = 0; q < 2; ++q) {
        int t2 = tid + q * 256;
        int nl = t2 >> 3, c8 = t2 & 7;
        int n = n0 + nl, c = c0 + c8 * 8;
        bf16x8 r;
        #pragma unroll
        for (int j = 0; j < 8; ++j)
            r[j] = (short)lds[(c8 * 8 + j) * 70 + nl];
        *reinterpret_cast<bf16x8*>(
            &xT[(size_t)b * 409600 + (size_t)((n >> 4) * 8 + (c >> 5)) * 512 +
                foff(n, c & 31)]) = r;
    }
}

// ---------------- K1b: barrier-free dual conv1x1, all-frag operands ----------------
__global__ __launch_bounds__(256) void k1b_conv(
    const ushort* __restrict__ xT,
    const ushort* __restrict__ gwb, const float* __restrict__ gb,
    const ushort* __restrict__ twb, const float* __restrict__ tb,
    ushort* __restrict__ gout, ushort* __restrict__ thT)
{
    int nt = blockIdx.x % NTB, b = blockIdx.x / NTB;
    int n0 = nt * 64;
    int tid = threadIdx.x, lane = tid & 63, w = tid >> 6;
    int lr = lane & 15, lg = lane >> 4;
    const ushort* xb = xT + (size_t)b * 409600;

    if (w < 2) {
        int o0 = w * 64;
        f32x4 acc[4][4] = {};
        #pragma unroll
        for (int kc = 0; kc < 8; ++kc) {
            bf16x8 a[4], bf[4];
            #pragma unroll
            for (int mi = 0; mi < 4; ++mi)
                a[mi] = *reinterpret_cast<const bf16x8*>(
                    &xb[(size_t)(((n0 >> 4) + mi) * 8 + kc) * 512 + lane * 8]);
            #pragma unroll
            for (int ni = 0; ni < 4; ++ni)
                bf[ni] = *reinterpret_cast<const bf16x8*>(
                    &gwb[(size_t)(((o0 >> 4) + ni) * 8 + kc) * 512 + lane * 8]);
            #pragma unroll
            for (int mi = 0; mi < 4; ++mi)
                #pragma unroll
                for (int ni = 0; ni < 4; ++ni)
                    acc[mi][ni] = __builtin_amdgcn_mfma_f32_16x16x32_bf16(
                        a[mi], bf[ni], acc[mi][ni], 0, 0, 0);
        }
        #pragma unroll
        for (int ni = 0; ni < 4; ++ni) {
            int o = o0 + ni * 16 + lr;
            float bs = gb[o];
            ushort* gp = &gout[((size_t)b * 128 + o) * 1600 + n0];
            #pragma unroll
            for (int mi = 0; mi < 4; ++mi) {
                ushort4 pk;
                pk.x = f2bf(acc[mi][ni][0] + bs);
                pk.y = f2bf(acc[mi][ni][1] + bs);
                pk.z = f2bf(acc[mi][ni][2] + bs);
                pk.w = f2bf(acc[mi][ni][3] + bs);
                *reinterpret_cast<ushort4*>(&gp[mi * 16 + lg * 4]) = pk;
            }
        }
    } else {
        int o0 = (w - 2) * 64;
        f32x4 acc[4][4] = {};
        #pragma unroll
        for (int kc = 0; kc < 8; ++kc) {
            bf16x8 a[4], bf[4];
            #pragma unroll
            for (int mi = 0; mi < 4; ++mi)
                a[mi] = *reinterpret_cast<const bf16x8*>(
                    &twb[(size_t)(((o0 >> 4) + mi) * 8 + kc) * 512 + lane * 8]);
            #pragma unroll
            for (int ni = 0; ni < 4; ++ni)
                bf[ni] = *reinterpret_cast<const bf16x8*>(
                    &xb[(size_t)(((n0 >> 4) + ni) * 8 + kc) * 512 + lane * 8]);
            #pragma unroll
            for (int mi = 0; mi < 4; ++mi)
                #pragma unroll
                for (int ni = 0; ni < 4; ++ni)
                    acc[mi][ni] = __builtin_amdgcn_mfma_f32_16x16x32_bf16(
                        a[mi], bf[ni], acc[mi][ni], 0, 0, 0);
        }
        // thT frag-swizzled: rows n (1600), k c (128): blocks (n>>4)*4 + (c>>5)
        #pragma unroll
        for (int mi = 0; mi < 4; ++mi) {
            float4 tbv = *reinterpret_cast<const float4*>(&tb[o0 + mi * 16 + lg * 4]);
            float tbb[4] = {tbv.x, tbv.y, tbv.z, tbv.w};
            int cq = o0 + mi * 16 + lg * 4;
            #pragma unroll
            for (int ni = 0; ni < 4; ++ni) {
                int n = n0 + ni * 16 + lr;
                ushort4 pk;
                pk.x = f2bf(acc[mi][ni][0] + tbb[0]);
                pk.y = f2bf(acc[mi][ni][1] + tbb[1]);
                pk.z = f2bf(acc[mi][ni][2] + tbb[2]);
                pk.w = f2bf(acc[mi][ni][3] + tbb[3]);
                *reinterpret_cast<ushort4*>(
                    &thT[(size_t)b * 204800 + (size_t)((n >> 4) * 4 + (cq >> 5)) * 512 +
                         foff(n, cq & 31)]) = pk;
            }
        }
    }
}

// ---------------- K2: PSP pooling; phiC row-major + phiT frag-swizzled ----------------
// phiT blocks per b: rows s(768), k c(128): (s>>4)*4 + (c>>5); b stride 98304 u16.
__global__ __launch_bounds__(256) void k2a_psp(const ushort* __restrict__ g,
                                               ushort* __restrict__ phiC,
                                               ushort* __restrict__ phiT)
{
    int idx = blockIdx.x * 256 + threadIdx.x;
    if (idx >= 64 * 128 * 768) return;
    int j = idx % 768;
    int bc = idx / 768;
    float outv = 0.f;
    if (j < 725) {
        int ls, off;
        if (j < 25)       { ls = 0; off = 0; }
        else if (j < 125) { ls = 2; off = 25; }
        else if (j < 325) { ls = 3; off = 125; }
        else              { ls = 4; off = 325; }
        int m = j - off;
        int flat = (bc << ls) * 25 + m;
        int a   = flat >> (7 + ls);
        int rem = flat & ((128 << ls) - 1);
        int c2  = rem >> ls;
        int k   = rem & ((1 << ls) - 1);
        int L   = 64 >> ls;
        const ushort* p = g + ((size_t)a << 13) + (c2 << 6) + k * L;
        float sum = 0.f;
        for (int q = 0; q < L; ++q) sum += bf2f(p[q]);
        outv = sum * (1.f / L);
    }
    ushort hv = f2bf(outv);
    phiC[idx] = hv;
    int b = bc >> 7, c = bc & 127;
    phiT[(size_t)b * 98304 + (size_t)((j >> 4) * 4 + (c >> 5)) * 512 + foff(j, c & 31)] = hv;
}

// ---------------- K3: E = exp(theta^T phi) + column-sum partials ----------------
// B-tile (64s x 128c = 16KB) staged once to LDS; A frags direct; E frag-swizzled out.
__global__ __launch_bounds__(256) void k3_expf(
    const ushort* __restrict__ thT, const ushort* __restrict__ phiT,
    ushort* __restrict__ E, float* __restrict__ psum, int b0)
{
    int blk = blockIdx.x;
    int st = blk % 12; blk /= 12;
    int nt = blk % 25; int bl = blk / 25;
    int b = b0 + bl;
    int n0 = nt * 64, s0 = st * 64;
    int tid = threadIdx.x, lane = tid & 63, w = tid >> 6;
    int lr = lane & 15, lg = lane >> 4;

    __shared__ ushort Bs[8192];     // 16 frag-blocks: (stile_local*4 + kc)
    __shared__ float red[64][4];

    {   // coalesced 16KB copy global->LDS (linear)
        const ushort* src = phiT + (size_t)b * 98304 + (size_t)(s0 >> 4) * 2048;
        #pragma unroll
        for (int t = 0; t < 4; ++t) {
            int o8 = (t * 256 + tid) * 8;
            *reinterpret_cast<bf16x8*>(&Bs[o8]) =
                *reinterpret_cast<const bf16x8*>(&src[o8]);
        }
    }
    bf16x8 A[4];
    #pragma unroll
    for (int kc = 0; kc < 4; ++kc)
        A[kc] = *reinterpret_cast<const bf16x8*>(
            &thT[(size_t)b * 204800 + (size_t)(((n0 >> 4) + w) * 4 + kc) * 512 + lane * 8]);
    __syncthreads();

    f32x4 acc[4] = {};
    #pragma unroll
    for (int kc = 0; kc < 4; ++kc)
        #pragma unroll
        for (int ni = 0; ni < 4; ++ni) {
            bf16x8 bb = *reinterpret_cast<const bf16x8*>(&Bs[(ni * 4 + kc) * 512 + lane * 8]);
            acc[ni] = __builtin_amdgcn_mfma_f32_16x16x32_bf16(A[kc], bb, acc[ni], 0, 0, 0);
        }

    // E frag-swizzled: rows n (p), k s: blocks (n>>4)*24 + (s>>5); bl stride 1228800 u16.
    size_t ebase = (size_t)bl * 1228800 + (size_t)(((n0 >> 4) + w) * 24 + (s0 >> 5)) * 512;
    #pragma unroll
    for (int ni = 0; ni < 4; ++ni) {
        float se = 0.f;
        float ex[4];
        #pragma unroll
        for (int r = 0; r < 4; ++r) { ex[r] = __expf(acc[ni][r]); se += ex[r]; }
        int scadd = (ni >> 1) * 512;
        int khi = ((ni & 1) * 2 + (lr >> 3)) & 3;
        #pragma unroll
        for (int r = 0; r < 4; ++r) {
            int p = lg * 4 + r;
            E[ebase + scadd + ((p | (khi << 4)) << 3) + (lr & 7)] = f2bf(ex[r]);
        }
        se += __shfl_xor(se, 16);
        se += __shfl_xor(se, 32);
        if (lg == 0) red[ni * 16 + lr][w] = se;
    }
    __syncthreads();
    if (tid < 64) {
        float z = red[tid][0] + red[tid][1] + red[tid][2] + red[tid][3];
        psum[((size_t)b * 768 + s0 + tid) * 25 + nt] = z;
    }
}

// ---------------- K4a: zinv[b][s] = 1/sum(psum partials) ----------------
__global__ __launch_bounds__(256) void k4a_zinv(const float* __restrict__ psum,
                                                float* __restrict__ zinv)
{
    int idx = blockIdx.x * 256 + threadIdx.x;
    if (idx >= 32 * 768) return;
    int s = idx % 768;
    const float* p = psum + (size_t)idx * 25;
    float z = 0.f;
    #pragma unroll
    for (int i = 0; i < 25; ++i) z += p[i];
    zinv[idx] = (s < 725) ? 1.f / z : 0.f;
}

// ---------------- K4b: phiZ (frag-swizzled, rows c, k s) = phiC * zinv[s] ----------------
// phiZ blocks per b: (c>>4)*24 + (s>>5); b stride 98304 u16.
__global__ __launch_bounds__(256) void k4b_scale(const ushort* __restrict__ phiC,
                                                 const float* __restrict__ zinv,
                                                 ushort* __restrict__ phiZ)
{
    int idx = blockIdx.x * 256 + threadIdx.x;   // 32*128*96
    int s8 = idx % 96, bc = idx / 96;
    int b = bc >> 7, c = bc & 127;
    int s0 = s8 * 8;
    bf16x8 v = *reinterpret_cast<const bf16x8*>(&phiC[(size_t)bc * 768 + s0]);
    const float* zp = &zinv[b * 768 + s0];
    bf16x8 r;
    #pragma unroll
    for (int j = 0; j < 8; ++j) r[j] = (short)f2bf(bf2f((ushort)v[j]) * zp[j]);
    *reinterpret_cast<bf16x8*>(
        &phiZ[(size_t)b * 98304 + (size_t)((c >> 4) * 24 + (s0 >> 5)) * 512 +
              foff(c, s0 & 31)]) = r;
}

// ---------------- K5: y = E @ phiZ^T, single-wave, depth-3 prefetch, frag loads ----------------
__global__ __launch_bounds__(64, 2) void k5_pv(
    const ushort* __restrict__ E, const ushort* __restrict__ phiZ,
    ushort* __restrict__ y, float* __restrict__ ypz, int b0)
{
    int ng = blockIdx.x % 100, bl = blockIdx.x / 100;
    int b = b0 + bl;
    int nrow = ng * 16;
    int lane = threadIdx.x;
    int lr = lane & 15, lg = lane >> 4;
    const ushort* Eb = E + (size_t)bl * 1228800 + (size_t)ng * 24 * 512 + lane * 8;
    const ushort* Pb = phiZ + (size_t)b * 98304 + lane * 8;

    f32x4 acc[8] = {};
    bf16x8 Ab[3], Bb[3][8];
    #pragma unroll
    for (int p = 0; p < 3; ++p) {
        Ab[p] = *reinterpret_cast<const bf16x8*>(&Eb[(size_t)p * 512]);
        #pragma unroll
        for (int cf = 0; cf < 8; ++cf)
            Bb[p][cf] = *reinterpret_cast<const bf16x8*>(&Pb[(size_t)(cf * 24 + p) * 512]);
    }
    #pragma unroll
    for (int kc = 0; kc < 24; ++kc) {
        int cur = kc % 3;
        bf16x8 a = Ab[cur];
        #pragma unroll
        for (int cf = 0; cf < 8; ++cf)
            acc[cf] = __builtin_amdgcn_mfma_f32_16x16x32_bf16(a, Bb[cur][cf], acc[cf], 0, 0, 0);
        if (kc + 3 < 24) {
            Ab[cur] = *reinterpret_cast<const bf16x8*>(&Eb[(size_t)(kc + 3) * 512]);
            #pragma unroll
            for (int cf = 0; cf < 8; ++cf)
                Bb[cur][cf] = *reinterpret_cast<const bf16x8*>(
                    &Pb[(size_t)(cf * 24 + kc + 3) * 512]);
        }
    }

    #pragma unroll
    for (int cf = 0; cf < 8; ++cf) {
        float se = 0.f;
        #pragma unroll
        for (int r = 0; r < 4; ++r) {
            ushort hv = f2bf(acc[cf][r]);
            y[((size_t)b * 1600 + nrow + lg * 4 + r) * 128 + cf * 16 + lr] = hv;
            se += __expf(bf2f(hv));
        }
        se += __shfl_xor(se, 16);
        se += __shfl_xor(se, 32);
        if (lane < 16)
            ypz[((size_t)b * 128 + cf * 16 + lane) * 100 + ng] = se;
    }
}

// ---------------- K6b: combine 100 partials -> 1/Z2 per (b,c) ----------------
__global__ void k6b_ycomb(const float* __restrict__ ypz, float* __restrict__ yzi)
{
    int idx = blockIdx.x * 256 + threadIdx.x;
    if (idx >= 64 * 128) return;
    const float* p = ypz + (size_t)idx * 100;
    float z = 0.f;
    for (int i = 0; i < 100; ++i) z += p[i];
    yzi[idx] = 1.f / z;
}

// ---------------- K7: softmax(y) -> conv W + residual + BN + ReLU ----------------
__global__ __launch_bounds__(256) void k7_final(
    const ushort* __restrict__ y, const float* __restrict__ yzi,
    const ushort* __restrict__ Wbf, const float* __restrict__ Wb,
    const float* __restrict__ x,
    const float* __restrict__ gamma, const float* __restrict__ beta,
    const float* __restrict__ mean, const float* __restrict__ var,
    float* __restrict__ out)
{
    int nt = blockIdx.x % NTB, b = blockIdx.x / NTB;
    int n0 = nt * 64;
    __shared__ ushort yl[64][136];
    __shared__ float scl[256], shl[256], wbl[256], zl[128];
    int t = threadIdx.x, lane = t & 63, w = t >> 6;
    {
        float sc = gamma[t] * rsqrtf(var[t] + 1e-5f);
        scl[t] = sc;
        shl[t] = beta[t] - mean[t] * sc;
        wbl[t] = Wb[t];
        if (t < 128) zl[t] = yzi[(size_t)b * 128 + t];
    }
    __syncthreads();
    int c8 = (t & 15) * 8, rr = t >> 4;
    #pragma unroll
    for (int p = 0; p < 4; ++p) {
        int r = rr + 16 * p;
        bf16x8 v = *reinterpret_cast<const bf16x8*>(
            &y[((size_t)b * 1600 + n0 + r) * 128 + c8]);
        bf16x8 pk;
        #pragma unroll
        for (int j = 0; j < 8; ++j) {
            float f = bf2f((ushort)v[j]);
            pk[j] = (short)f2bf(__expf(f) * zl[c8 + j]);
        }
        *reinterpret_cast<bf16x8*>(&yl[r][c8]) = pk;
    }
    __syncthreads();
    int lr = lane & 15, lg = lane >> 4;
    int o0 = w * 64;
    f32x4 acc[4][4] = {};
    #pragma unroll
    for (int kc = 0; kc < 4; ++kc) {
        bf16x8 af[4];
        #pragma unroll
        for (int mi = 0; mi < 4; ++mi)
            af[mi] = *reinterpret_cast<const bf16x8*>(
                &Wbf[(size_t)(((o0 >> 4) + mi) * 4 + kc) * 512 + lane * 8]);
        #pragma unroll
        for (int ni = 0; ni < 4; ++ni) {
            bf16x8 bfrag = *reinterpret_cast<const bf16x8*>(&yl[ni * 16 + lr][kc * 32 + lg * 8]);
            #pragma unroll
            for (int mi = 0; mi < 4; ++mi)
                acc[mi][ni] = __builtin_amdgcn_mfma_f32_16x16x32_bf16(
                    af[mi], bfrag, acc[mi][ni], 0, 0, 0);
        }
    }
    #pragma unroll
    for (int mi = 0; mi < 4; ++mi)
        #pragma unroll
        for (int ni = 0; ni < 4; ++ni) {
            int n = n0 + ni * 16 + lr;
            #pragma unroll
            for (int r = 0; r < 4; ++r) {
                int o = o0 + mi * 16 + lg * 4 + r;
                size_t off = ((size_t)b * 256 + o) * 1600 + n;
                float v = (acc[mi][ni][r] + wbl[o] + x[off]) * scl[o] + shl[o];
                out[off] = fmaxf(v, 0.f);
            }
        }
}

extern "C" void kernel_launch(void* const* d_in, const int* in_sizes, int n_in,
                              void* d_out, int out_size, void* d_ws, size_t ws_size,
                              hipStream_t stream)
{
    const float* x   = (const float*)d_in[0];
    const float* gw  = (const float*)d_in[1];
    const float* gb  = (const float*)d_in[2];
    const float* tw  = (const float*)d_in[3];
    const float* tb  = (const float*)d_in[4];
    const float* Ww  = (const float*)d_in[5];
    const float* Wb  = (const float*)d_in[6];
    const float* bng = (const float*)d_in[7];
    const float* bnb = (const float*)d_in[8];
    const float* bnm = (const float*)d_in[9];
    const float* bnv = (const float*)d_in[10];
    float* out = (float*)d_out;

    char* base = (char*)d_ws;
    ushort* thT  = (ushort*)(base);               // 26,214,400 B (frag-swz)
    ushort* gout = (ushort*)(base + 26214400);    // 26,214,400 B (reused as y)
    ushort* phiC = (ushort*)(base + 52428800);    // 12,582,912 B (row-major)
    ushort* phiT = (ushort*)(base + 65011712);    // 12,582,912 B (frag-swz)
    float* psum  = (float*)(base + 77594624);     //  4,915,200 B
    ushort* phiZ = (ushort*)(base + 82509824);    // 12,582,912 B (frag-swz)
    float* zinv  = (float*)(base + 95092736);     //    196,608 B
    float* ypz   = (float*)(base + 95289344);     //  3,276,800 B
    float* yzi   = (float*)(base + 98566144);     //     32,768 B
    ushort* Wbf  = (ushort*)(base + 98598912);    //     65,536 B (frag-swz)
    ushort* gwb  = (ushort*)(base + 98664448);    //     65,536 B (frag-swz)
    ushort* twb  = (ushort*)(base + 98729984);    //     65,536 B (frag-swz)
    ushort* yv   = gout;                          // alias: gout dead after k2a
    // d_out region as scratch: xT (52.4 MB frag-swz, dead after k1b),
    // then E per half (78.6 MB frag-swz, dead after k5). k7 rewrites out last.
    ushort* xT   = (ushort*)d_out;
    ushort* E    = (ushort*)d_out;

    k0_wconv<<<48, 256, 0, stream>>>(gw, tw, Ww, gwb, twb, Wbf);
    k1a_xpose<<<64 * 4 * NTB, 256, 0, stream>>>(x, xT);
    k1b_conv<<<64 * NTB, 256, 0, stream>>>(xT, gwb, gb, twb, tb, gout, thT);
    k2a_psp<<<(64 * 128 * 768) / 256, 256, 0, stream>>>(gout, phiC, phiT);

    // half 0: batches 0..31
    k3_expf<<<32 * 25 * 12, 256, 0, stream>>>(thT, phiT, E, psum, 0);
    k4a_zinv<<<96, 256, 0, stream>>>(psum, zinv);
    k4b_scale<<<1536, 256, 0, stream>>>(phiC, zinv, phiZ);
    k5_pv<<<32 * 100, 64, 0, stream>>>(E, phiZ, yv, ypz, 0);

    // half 1: batches 32..63
    k3_expf<<<32 * 25 * 12, 256, 0, stream>>>(thT, phiT, E, psum, 32);
    k4a_zinv<<<96, 256, 0, stream>>>(psum + (size_t)32 * 768 * 25, zinv);
    k4b_scale<<<1536, 256, 0, stream>>>(phiC + (size_t)32 * 128 * 768, zinv,
                                        phiZ + (size_t)32 * 98304);
    k5_pv<<<32 * 100, 64, 0, stream>>>(E, phiZ, yv, ypz, 32);

    k6b_ycomb<<<32, 256, 0, stream>>>(ypz, yzi);
    k7_final<<<64 * NTB, 256, 0, stream>>>(yv, yzi, Wbf, Wb, x, bng, bnb, bnm, bnv, out);
}